// Round 24
// baseline (128.162 us; speedup 1.0000x reference)
//
#include <hip/hip_runtime.h>
#include <cstdint>

#define BB 16
#define MM 128
#define TT 12000
constexpr int BT = BB * TT; // 192000

// Q4-interleaved scan layout: element (row b, pos t), t=4g+j lives at
// q[(g*16 + b)*4 + j]. Group = 256 B. SB = 4 groups = 1024 B.
// Chunk = 24 SBs = 24576 B = 1536 float4. 32 chunks = 768 SBs (750 real).

// K1: per-column stats over the M axis, sequential in m (reference order).
// anti-fma via `#pragma clang fp contract(off)` (proven round 13).
__global__ void k1_colstats(const float* __restrict__ mel,
                            float* __restrict__ ssq,
                            float* __restrict__ dotv,
                            float* __restrict__ cmean,
                            unsigned int* __restrict__ counts) {
    if (blockIdx.x == 0 && blockIdx.y == 0 && threadIdx.x < 8)
        counts[threadIdx.x] = 0u;
    const int b = blockIdx.y;
    const int t = blockIdx.x * blockDim.x + threadIdx.x;
    if (t >= TT) return;
    const float* base = mel + (size_t)b * MM * TT;
    float accd = 0.f, accq = 0.f, accs = 0.f;
    {
#pragma clang fp contract(off)
        for (int m = 0; m < MM; ++m) {
            const float* rowp = base + (size_t)m * TT;
            float cur = rowp[t];
            float prev = (t > 0) ? rowp[t - 1] : 0.f;
            accd += prev * cur;
            accq += cur * cur;
            accs += cur;
        }
    }
    size_t i = (size_t)b * TT + t;
    ssq[i] = accq; dotv[i] = accd; cmean[i] = accs * (1.0f / MM);
}

// kA: temporal = 1 - std(smooth, ddof=1). Row staged to LDS once.
__global__ void kA_temporal(const float* __restrict__ cmean,
                            float* __restrict__ temporal) {
    const int b = blockIdx.x;
    const int tid = threadIdx.x;
    __shared__ __align__(16) float row_s[TT];
    __shared__ float red[256];
    __shared__ float mean_s;
    const float4* c4 = (const float4*)(cmean + (size_t)b * TT);
    float4* r4 = (float4*)row_s;
    for (int i = tid; i < TT / 4; i += 256) r4[i] = c4[i];
    __syncthreads();

    float s = 0.f;
    for (int t = tid; t < TT; t += 256) {
        float v = 0.f;
        int lo = t - 2 < 0 ? 0 : t - 2;
        int hi = t + 2 >= TT ? TT - 1 : t + 2;
        for (int j = lo; j <= hi; ++j) v += row_s[j];
        s += v / 5.0f;
    }
    red[tid] = s; __syncthreads();
    for (int o = 128; o > 0; o >>= 1) {
        if (tid < o) red[tid] += red[tid + o];
        __syncthreads();
    }
    if (tid == 0) mean_s = red[0] / (float)TT;
    __syncthreads();
    float mean = mean_s;
    float ss = 0.f;
    for (int t = tid; t < TT; t += 256) {
        float v = 0.f;
        int lo = t - 2 < 0 ? 0 : t - 2;
        int hi = t + 2 >= TT ? TT - 1 : t + 2;
        for (int j = lo; j <= hi; ++j) v += row_s[j];
        float sm = v / 5.0f - mean;
        ss += sm * sm;
    }
    red[tid] = ss; __syncthreads();
    for (int o = 128; o > 0; o >>= 1) {
        if (tid < o) red[tid] += red[tid + o];
        __syncthreads();
    }
    if (tid == 0) {
        float var = red[0] / (float)(TT - 1);
        temporal[b] = 1.0f - sqrtf(var);
    }
}

// kB: cons — same arithmetic as the passing version; additionally writes
// the Q4-interleaved copy for the scan (same value, extra store only).
__global__ void kB_cons(const float* __restrict__ ssq,
                        const float* __restrict__ dotv,
                        const float* __restrict__ spec,
                        const float* __restrict__ temporal,
                        const float* __restrict__ wraw,
                        float* __restrict__ cons,
                        float* __restrict__ consq) {
    const int idx = blockIdx.x * 256 + threadIdx.x;
    const int b = idx / TT;
    const int t = idx - b * TT;
    float x0 = wraw[0], x1 = wraw[1], x2 = wraw[2];
    float mx = fmaxf(x0, fmaxf(x1, x2));
    float e0 = expf(x0 - mx), e1 = expf(x1 - mx), e2 = expf(x2 - mx);
    float es = (e0 + e1) + e2;
    float w0 = e0 / es, w1 = e1 / es, w2 = e2 / es;
    float mel_sim, spec_sim;
    if (t == 0) { mel_sim = 0.f; spec_sim = 1.f; }
    else {
        float na = fmaxf(sqrtf(ssq[idx - 1]), 1e-8f);
        float nb = fmaxf(sqrtf(ssq[idx]),     1e-8f);
        float den = na * nb; asm volatile("" : "+v"(den));
        mel_sim = dotv[idx] / den;
        float d = fabsf(spec[idx] - spec[idx - 1]);
        spec_sim = 1.0f / (1.0f + d);
    }
    float pa = w0 * mel_sim;     asm volatile("" : "+v"(pa));
    float pb = w1 * spec_sim;    asm volatile("" : "+v"(pb));
    float pc = w2 * temporal[b]; asm volatile("" : "+v"(pc));
    float c = (pa + pb) + pc;
    cons[idx] = c;
    consq[((t >> 2) * 16 + b) * 4 + (t & 3)] = c;
}

// One SB (16 elems, 16 lanes lockstep): counted pure-read lgkm wait
// (ring of 4 SBs -> 16 reads outstanding, drain oldest 4), 16 chained
// adds (bitwise reference order, carry in/out via %0, snapshot BEFORE
// the prefetch reads — round-5 WAR discipline), 4 CS stores to global
// (fire-and-forget vmcnt), 4 prefetch ds_reads 4 SBs ahead.
#define SB16(a0,a1,a2,a3, b0,b1,b2,b3, c0,c1,c2,c3, d0,d1,d2,d3, S0,S1,S2,S3, P0,P1,P2,P3) \
    "s_waitcnt lgkmcnt(12)\n\t" \
    "v_add_f32 v" a0 ", %0, v" a0 "\n\t" \
    "v_add_f32 v" a1 ", v" a0 ", v" a1 "\n\t" \
    "v_add_f32 v" a2 ", v" a1 ", v" a2 "\n\t" \
    "v_add_f32 v" a3 ", v" a2 ", v" a3 "\n\t" \
    "v_add_f32 v" b0 ", v" a3 ", v" b0 "\n\t" \
    "v_add_f32 v" b1 ", v" b0 ", v" b1 "\n\t" \
    "v_add_f32 v" b2 ", v" b1 ", v" b2 "\n\t" \
    "v_add_f32 v" b3 ", v" b2 ", v" b3 "\n\t" \
    "v_add_f32 v" c0 ", v" b3 ", v" c0 "\n\t" \
    "v_add_f32 v" c1 ", v" c0 ", v" c1 "\n\t" \
    "v_add_f32 v" c2 ", v" c1 ", v" c2 "\n\t" \
    "v_add_f32 v" c3 ", v" c2 ", v" c3 "\n\t" \
    "v_add_f32 v" d0 ", v" c3 ", v" d0 "\n\t" \
    "v_add_f32 v" d1 ", v" d0 ", v" d1 "\n\t" \
    "v_add_f32 v" d2 ", v" d1 ", v" d2 "\n\t" \
    "v_add_f32 v" d3 ", v" d2 ", v" d3 "\n\t" \
    "v_mov_b32 %0, v" d3 "\n\t" \
    "global_store_dwordx4 v40, v[" a0 ":" a3 "], %1 offset:" S0 "\n\t" \
    "global_store_dwordx4 v40, v[" b0 ":" b3 "], %1 offset:" S1 "\n\t" \
    "global_store_dwordx4 v40, v[" c0 ":" c3 "], %1 offset:" S2 "\n\t" \
    "global_store_dwordx4 v40, v[" d0 ":" d3 "], %1 offset:" S3 "\n\t" \
    "ds_read_b128 v[" a0 ":" a3 "], v41 offset:" P0 "\n\t" \
    "ds_read_b128 v[" b0 ":" b3 "], v41 offset:" P1 "\n\t" \
    "ds_read_b128 v[" c0 ":" c3 "], v41 offset:" P2 "\n\t" \
    "ds_read_b128 v[" d0 ":" d3 "], v41 offset:" P3 "\n\t"

// kC: chunked double-buffered 16-lane SIMT scan (round-20 structure with
// REGISTER-BATCHED staging). Per chunk c: threads 64..255 stage chunk c+1
// (8 independent float4 loads into regs, then 8 LDS writes — one HBM/L3
// latency total, not 8 serialized) while wave-0 lanes 0..15 scan chunk c
// from LDS (pure-read lgkm ring) storing CS to global Q4 fire-and-forget.
// Carry crosses chunks via "+v". SBs 750..767 are past every row's end.
__global__ void __launch_bounds__(256)
kC_scan16(const float* __restrict__ consq,
          float* __restrict__ CSq) {
    const int tid = threadIdx.x;
    __shared__ __align__(16) float lbuf[2 * 6144 + 1024];  // 2x24KB + 4KB pad
    float4* b4 = (float4*)lbuf;
    const float4* src4 = (const float4*)consq;

    // stage chunk 0 (all 256 threads, 6 float4 each)
    for (int i = tid; i < 1536; i += 256) b4[i] = src4[i];
    __syncthreads();

    float carry = 0.f;
    for (int c = 0; c < 32; ++c) {
        if (tid >= 64 && c + 1 < 32) {
            const float4* s4 = src4 + (size_t)(c + 1) * 1536;
            float4* d4 = b4 + (size_t)((c + 1) & 1) * 1536;
            const int lane = tid - 64;
            float4 tmp[8];
#pragma unroll
            for (int i = 0; i < 8; ++i) tmp[i] = s4[lane + 192 * i];
#pragma unroll
            for (int i = 0; i < 8; ++i) d4[lane + 192 * i] = tmp[i];
        }
        if (tid < BB) {
            uint32_t laddr = (uint32_t)(uintptr_t)(lbuf + (size_t)(c & 1) * 6144)
                           + (uint32_t)(tid * 16);
            uint32_t goff = (uint32_t)(c * 24576 + tid * 16);
            asm volatile(
                "v_mov_b32 v40, %3\n\t"
                "v_mov_b32 v41, %2\n\t"
                // prologue: prefetch SBs 0..3 of this chunk (16 reads)
                "ds_read_b128 v[48:51],   v41 offset:0\n\t"
                "ds_read_b128 v[52:55],   v41 offset:256\n\t"
                "ds_read_b128 v[56:59],   v41 offset:512\n\t"
                "ds_read_b128 v[60:63],   v41 offset:768\n\t"
                "ds_read_b128 v[64:67],   v41 offset:1024\n\t"
                "ds_read_b128 v[68:71],   v41 offset:1280\n\t"
                "ds_read_b128 v[72:75],   v41 offset:1536\n\t"
                "ds_read_b128 v[76:79],   v41 offset:1792\n\t"
                "ds_read_b128 v[80:83],   v41 offset:2048\n\t"
                "ds_read_b128 v[84:87],   v41 offset:2304\n\t"
                "ds_read_b128 v[88:91],   v41 offset:2560\n\t"
                "ds_read_b128 v[92:95],   v41 offset:2816\n\t"
                "ds_read_b128 v[96:99],   v41 offset:3072\n\t"
                "ds_read_b128 v[100:103], v41 offset:3328\n\t"
                "ds_read_b128 v[104:107], v41 offset:3584\n\t"
                "ds_read_b128 v[108:111], v41 offset:3840\n\t"
                "s_mov_b32 s20, 6\n\t"   // 6 iters x 4 SBs = 24 SBs
                "3:\n\t"
                SB16("48","49","50","51", "52","53","54","55",
                     "56","57","58","59", "60","61","62","63",
                     "0","256","512","768", "4096","4352","4608","4864")
                SB16("64","65","66","67", "68","69","70","71",
                     "72","73","74","75", "76","77","78","79",
                     "1024","1280","1536","1792", "5120","5376","5632","5888")
                SB16("80","81","82","83", "84","85","86","87",
                     "88","89","90","91", "92","93","94","95",
                     "2048","2304","2560","2816", "6144","6400","6656","6912")
                SB16("96","97","98","99", "100","101","102","103",
                     "104","105","106","107", "108","109","110","111",
                     "3072","3328","3584","3840", "7168","7424","7680","7936")
                "v_add_u32 v40, 0x1000, v40\n\t"
                "v_add_u32 v41, 0x1000, v41\n\t"
                "s_sub_u32 s20, s20, 1\n\t"
                "s_cmp_lg_u32 s20, 0\n\t"
                "s_cbranch_scc1 3b\n\t"
                // drain reads (tail prefetches read pad/other buffer; discarded)
                "s_waitcnt lgkmcnt(0)\n\t"
                : "+v"(carry)
                : "s"(CSq), "v"(laddr), "v"(goff)
                : "v40", "v41",
                  "v48", "v49", "v50", "v51", "v52", "v53", "v54", "v55",
                  "v56", "v57", "v58", "v59", "v60", "v61", "v62", "v63",
                  "v64", "v65", "v66", "v67", "v68", "v69", "v70", "v71",
                  "v72", "v73", "v74", "v75", "v76", "v77", "v78", "v79",
                  "v80", "v81", "v82", "v83", "v84", "v85", "v86", "v87",
                  "v88", "v89", "v90", "v91", "v92", "v93", "v94", "v95",
                  "v96", "v97", "v98", "v99", "v100", "v101", "v102", "v103",
                  "v104", "v105", "v106", "v107", "v108", "v109", "v110", "v111",
                  "s20", "scc", "memory");
        }
        __syncthreads();
    }
    if (tid < BB) asm volatile("s_waitcnt vmcnt(0)" ::: "memory");
}

// kD: flags ONLY — per-iteration "any nonzero adjustment" on the
// never-done trajectory. k_final recomputes step/cand (bitwise same).
__global__ void kD_flags(const float* __restrict__ cons,
                         const float* __restrict__ CSq,
                         const float* __restrict__ init,
                         unsigned int* __restrict__ counts) {
    const int idx = blockIdx.x * 256 + threadIdx.x;
    const int b = idx / TT;
    const int t = idx - b * TT;
    __shared__ unsigned sflag[5];
    if (threadIdx.x < 5) sflag[threadIdx.x] = 0u;
    __syncthreads();

    int lo = t - 2; if (lo < 0) lo = 0;
    int hi = t + 3; if (hi > TT) hi = TT;
    int uh = hi - 1;
    float csH = CSq[((uh >> 2) * 16 + b) * 4 + (uh & 3)];
    float csL = 0.f;
    if (lo > 0) {
        int ul = lo - 1;
        csL = CSq[((ul >> 2) * 16 + b) * 4 + (ul & 3)];
    }
    float local = (csH - csL) / (float)(hi - lo);
    float dir = (local > 0.7f) ? -0.1f : ((local < 0.4f) ? 0.1f : 0.0f);
    bool interior = (t >= 1) && (t <= TT - 2);
    float step = interior ? dir : 0.0f;
    float g = (t == 0) ? 0.f : fabsf(cons[idx] - cons[idx - 1]);
    float cand = (g > 0.15f) ? 1.f : 0.f;
    float r = init[idx];
    bool nz[5];
#pragma unroll
    for (int j = 0; j < 5; ++j) {
        float adj = (fmaxf(cand, r) > 0.5f) ? step : 0.0f;
        nz[j] = (adj != 0.0f);
        r = fminf(fmaxf(r + adj, 0.0f), 1.0f);
    }
    const int lane = threadIdx.x & 63;
#pragma unroll
    for (int j = 0; j < 5; ++j) {
        unsigned long long mb = __ballot(nz[j]);
        if (lane == 0 && mb) atomicOr(&sflag[j], 1u);   // LDS-scope, cheap
    }
    __syncthreads();
    if (threadIdx.x < 5 && sflag[threadIdx.x]) counts[threadIdx.x] = 1u;
}

// K_final: recompute step/cand (bitwise same as kD) and replay the 5-iter
// trajectory, freezing at the first iteration whose flag is 0.
__global__ void k_final(const float* __restrict__ cons,
                        const float* __restrict__ CSq,
                        const float* __restrict__ init,
                        const unsigned int* __restrict__ counts,
                        float* __restrict__ outp) {
    const int idx = blockIdx.x * 256 + threadIdx.x;
    const int b = idx / TT;
    const int t = idx - b * TT;

    int lo = t - 2; if (lo < 0) lo = 0;
    int hi = t + 3; if (hi > TT) hi = TT;
    int uh = hi - 1;
    float csH = CSq[((uh >> 2) * 16 + b) * 4 + (uh & 3)];
    float csL = 0.f;
    if (lo > 0) {
        int ul = lo - 1;
        csL = CSq[((ul >> 2) * 16 + b) * 4 + (ul & 3)];
    }
    float local = (csH - csL) / (float)(hi - lo);
    float dir = (local > 0.7f) ? -0.1f : ((local < 0.4f) ? 0.1f : 0.0f);
    bool interior = (t >= 1) && (t <= TT - 2);
    float step = interior ? dir : 0.0f;
    float g = (t == 0) ? 0.f : fabsf(cons[idx] - cons[idx - 1]);
    float cand = (g > 0.15f) ? 1.f : 0.f;

    float r = init[idx];
    unsigned c[5];
#pragma unroll
    for (int j = 0; j < 5; ++j) c[j] = counts[j];
#pragma unroll
    for (int j = 0; j < 5; ++j) {
        if (c[j] == 0u) break;
        float adj = (fmaxf(cand, r) > 0.5f) ? step : 0.0f;
        r = fminf(fmaxf(r + adj, 0.0f), 1.0f);
    }
    outp[idx] = r;
}

extern "C" void kernel_launch(void* const* d_in, const int* in_sizes, int n_in,
                              void* d_out, int out_size, void* d_ws, size_t ws_size,
                              hipStream_t stream) {
    const float* mel  = (const float*)d_in[0];
    const float* spec = (const float*)d_in[1];
    const float* init = (const float*)d_in[2];
    const float* wts  = (const float*)d_in[3];

    float* ws = (float*)d_ws;
    float* ssq   = ws;                 // 192000
    float* dotv  = ws + 192000;        // 192000
    float* cmean = ws + 384000;        // 192000
    float* cons  = ws + 576000;        // 192000 (row-major)
    float* consq = ws + 768000;        // 196608 (Q4, padded to 768 SBs)
    float* CSq   = ws + 964608;        // 196608 (Q4, padded to 768 SBs)
    float* temporal = ws + 1161216;    // 16
    unsigned int* counts = (unsigned int*)(ws + 1161232); // 8 u32

    dim3 g1((TT + 255) / 256, BB);
    k1_colstats<<<g1, 256, 0, stream>>>(mel, ssq, dotv, cmean, counts);
    kA_temporal<<<BB, 256, 0, stream>>>(cmean, temporal);
    kB_cons<<<BT / 256, 256, 0, stream>>>(ssq, dotv, spec, temporal, wts, cons, consq);
    kC_scan16<<<1, 256, 0, stream>>>(consq, CSq);
    kD_flags<<<BT / 256, 256, 0, stream>>>(cons, CSq, init, counts);
    k_final<<<BT / 256, 256, 0, stream>>>(cons, CSq, init, counts, (float*)d_out);
}

// Round 25
// 125.441 us; speedup vs baseline: 1.0217x; 1.0217x over previous
//
#include <hip/hip_runtime.h>
#include <cstdint>

#define BB 16
#define MM 128
#define TT 12000
constexpr int BT = BB * TT; // 192000

// Q4-interleaved scan layout: element (row b, pos t), t=4g+j lives at
// q[(g*16 + b)*4 + j]  (one float4 per (group, row); 16 rows contiguous
// per group -> a 16-lane quad access covers 256 contiguous bytes).

// K1: per-column stats over the M axis, sequential in m (reference order).
// anti-fma via `#pragma clang fp contract(off)` (proven round 13).
__global__ void k1_colstats(const float* __restrict__ mel,
                            float* __restrict__ ssq,
                            float* __restrict__ dotv,
                            float* __restrict__ cmean,
                            unsigned int* __restrict__ counts) {
    if (blockIdx.x == 0 && blockIdx.y == 0 && threadIdx.x < 8)
        counts[threadIdx.x] = 0u;
    const int b = blockIdx.y;
    const int t = blockIdx.x * blockDim.x + threadIdx.x;
    if (t >= TT) return;
    const float* base = mel + (size_t)b * MM * TT;
    float accd = 0.f, accq = 0.f, accs = 0.f;
    {
#pragma clang fp contract(off)
        for (int m = 0; m < MM; ++m) {
            const float* rowp = base + (size_t)m * TT;
            float cur = rowp[t];
            float prev = (t > 0) ? rowp[t - 1] : 0.f;
            accd += prev * cur;
            accq += cur * cur;
            accs += cur;
        }
    }
    size_t i = (size_t)b * TT + t;
    ssq[i] = accq; dotv[i] = accd; cmean[i] = accs * (1.0f / MM);
}

// kA: temporal = 1 - std(smooth, ddof=1). Row staged to LDS once.
__global__ void kA_temporal(const float* __restrict__ cmean,
                            float* __restrict__ temporal) {
    const int b = blockIdx.x;
    const int tid = threadIdx.x;
    __shared__ __align__(16) float row_s[TT];
    __shared__ float red[256];
    __shared__ float mean_s;
    const float4* c4 = (const float4*)(cmean + (size_t)b * TT);
    float4* r4 = (float4*)row_s;
    for (int i = tid; i < TT / 4; i += 256) r4[i] = c4[i];
    __syncthreads();

    float s = 0.f;
    for (int t = tid; t < TT; t += 256) {
        float v = 0.f;
        int lo = t - 2 < 0 ? 0 : t - 2;
        int hi = t + 2 >= TT ? TT - 1 : t + 2;
        for (int j = lo; j <= hi; ++j) v += row_s[j];
        s += v / 5.0f;
    }
    red[tid] = s; __syncthreads();
    for (int o = 128; o > 0; o >>= 1) {
        if (tid < o) red[tid] += red[tid + o];
        __syncthreads();
    }
    if (tid == 0) mean_s = red[0] / (float)TT;
    __syncthreads();
    float mean = mean_s;
    float ss = 0.f;
    for (int t = tid; t < TT; t += 256) {
        float v = 0.f;
        int lo = t - 2 < 0 ? 0 : t - 2;
        int hi = t + 2 >= TT ? TT - 1 : t + 2;
        for (int j = lo; j <= hi; ++j) v += row_s[j];
        float sm = v / 5.0f - mean;
        ss += sm * sm;
    }
    red[tid] = ss; __syncthreads();
    for (int o = 128; o > 0; o >>= 1) {
        if (tid < o) red[tid] += red[tid + o];
        __syncthreads();
    }
    if (tid == 0) {
        float var = red[0] / (float)(TT - 1);
        temporal[b] = 1.0f - sqrtf(var);
    }
}

// kB: cons — same arithmetic as the passing version; additionally writes
// the Q4-interleaved copy for the scan (same value, extra store only).
__global__ void kB_cons(const float* __restrict__ ssq,
                        const float* __restrict__ dotv,
                        const float* __restrict__ spec,
                        const float* __restrict__ temporal,
                        const float* __restrict__ wraw,
                        float* __restrict__ cons,
                        float* __restrict__ consq) {
    const int idx = blockIdx.x * 256 + threadIdx.x;
    const int b = idx / TT;
    const int t = idx - b * TT;
    float x0 = wraw[0], x1 = wraw[1], x2 = wraw[2];
    float mx = fmaxf(x0, fmaxf(x1, x2));
    float e0 = expf(x0 - mx), e1 = expf(x1 - mx), e2 = expf(x2 - mx);
    float es = (e0 + e1) + e2;
    float w0 = e0 / es, w1 = e1 / es, w2 = e2 / es;
    float mel_sim, spec_sim;
    if (t == 0) { mel_sim = 0.f; spec_sim = 1.f; }
    else {
        float na = fmaxf(sqrtf(ssq[idx - 1]), 1e-8f);
        float nb = fmaxf(sqrtf(ssq[idx]),     1e-8f);
        float den = na * nb; asm volatile("" : "+v"(den));
        mel_sim = dotv[idx] / den;
        float d = fabsf(spec[idx] - spec[idx - 1]);
        spec_sim = 1.0f / (1.0f + d);
    }
    float pa = w0 * mel_sim;     asm volatile("" : "+v"(pa));
    float pb = w1 * spec_sim;    asm volatile("" : "+v"(pb));
    float pc = w2 * temporal[b]; asm volatile("" : "+v"(pc));
    float c = (pa + pb) + pc;
    cons[idx] = c;
    consq[((t >> 2) * 16 + b) * 4 + (t & 3)] = c;
}

// ROUND-18 PROVEN SCAN: one group = 4 dependent adds (bitwise the
// reference cumsum chain), carry snapshot BEFORE the prefetch load
// (round-5 WAR discipline), Q4 store (256 contiguous bytes), prefetch
// load 24 groups ahead; ONE vmcnt(40) wait per 4-group sub-batch.
#define SCQ(Q0a,Q0b,Q0c,Q0d, Q1a,Q1b,Q1c,Q1d, Q2a,Q2b,Q2c,Q2d, Q3a,Q3b,Q3c,Q3d) \
    "s_waitcnt vmcnt(40)\n\t" \
    "v_add_f32 v" Q0a ", v43, v" Q0a "\n\t" \
    "v_add_f32 v" Q0b ", v" Q0a ", v" Q0b "\n\t" \
    "v_add_f32 v" Q0c ", v" Q0b ", v" Q0c "\n\t" \
    "v_add_f32 v" Q0d ", v" Q0c ", v" Q0d "\n\t" \
    "v_add_f32 v" Q1a ", v" Q0d ", v" Q1a "\n\t" \
    "v_add_f32 v" Q1b ", v" Q1a ", v" Q1b "\n\t" \
    "v_add_f32 v" Q1c ", v" Q1b ", v" Q1c "\n\t" \
    "v_add_f32 v" Q1d ", v" Q1c ", v" Q1d "\n\t" \
    "v_add_f32 v" Q2a ", v" Q1d ", v" Q2a "\n\t" \
    "v_add_f32 v" Q2b ", v" Q2a ", v" Q2b "\n\t" \
    "v_add_f32 v" Q2c ", v" Q2b ", v" Q2c "\n\t" \
    "v_add_f32 v" Q2d ", v" Q2c ", v" Q2d "\n\t" \
    "v_add_f32 v" Q3a ", v" Q2d ", v" Q3a "\n\t" \
    "v_add_f32 v" Q3b ", v" Q3a ", v" Q3b "\n\t" \
    "v_add_f32 v" Q3c ", v" Q3b ", v" Q3c "\n\t" \
    "v_add_f32 v" Q3d ", v" Q3c ", v" Q3d "\n\t" \
    "v_mov_b32 v43, v" Q3d "\n\t" \
    "global_store_dwordx4 v40, v[" Q0a ":" Q0d "], %1 offset:0\n\t" \
    "global_store_dwordx4 v40, v[" Q1a ":" Q1d "], %1 offset:256\n\t" \
    "global_store_dwordx4 v40, v[" Q2a ":" Q2d "], %1 offset:512\n\t" \
    "global_store_dwordx4 v40, v[" Q3a ":" Q3d "], %1 offset:768\n\t" \
    "global_load_dwordx4 v[" Q0a ":" Q0d "], v42, %0 offset:0\n\t" \
    "global_load_dwordx4 v[" Q1a ":" Q1d "], v42, %0 offset:256\n\t" \
    "global_load_dwordx4 v[" Q2a ":" Q2d "], v42, %0 offset:512\n\t" \
    "global_load_dwordx4 v[" Q3a ":" Q3d "], v42, %0 offset:768\n\t" \
    "v_add_u32 v40, 0x400, v40\n\t" \
    "v_add_u32 v42, 0x400, v42\n\t"

// kC: 16-lane SIMT scan (round-18 asm verbatim, wave 0) + DECOUPLED L2
// warmers (waves 1-3): same workgroup -> same CU -> same XCD L2, so the
// warmers' streaming reads pull consq into the LOCAL L2 (~200 cyc) ahead
// of wave-0's ring loads (remote-L2 ~1300 cyc otherwise). No barriers —
// the warmers run free and finish early (round-22's failure was barrier
// coupling + per-iteration waits; fixed: split load/use loops, no sync).
__global__ void __launch_bounds__(256)
kC_scan16(const float* __restrict__ consq,
          float* __restrict__ CSq) {
    const int tid = threadIdx.x;
    if (tid >= 64) {
        // warmers: stream all 768 KB of consq (+pad) into local L2.
        const float4* s4 = (const float4*)consq;
        const int lane = tid - 64;
        for (int it = 0; it < 32; ++it) {
            float4 tmp[8];
#pragma unroll
            for (int i = 0; i < 8; ++i)
                tmp[i] = s4[(size_t)it * 1536 + lane + 192 * i];
#pragma unroll
            for (int i = 0; i < 8; ++i)
                asm volatile("" :: "v"(tmp[i].x), "v"(tmp[i].y),
                                   "v"(tmp[i].z), "v"(tmp[i].w));
        }
        return;
    }
    const int r = tid;
    if (r >= BB) return;
    uint32_t voff = (uint32_t)(r * 16);   // per-lane byte offset in a group
    asm volatile(
        "v_mov_b32 v40, %2\n\t"
        "v_mov_b32 v43, 0\n\t"
        // prologue: fill 24-quad ring (groups 0..23)
        "global_load_dwordx4 v[48:51],   v40, %0 offset:0\n\t"
        "global_load_dwordx4 v[52:55],   v40, %0 offset:256\n\t"
        "global_load_dwordx4 v[56:59],   v40, %0 offset:512\n\t"
        "global_load_dwordx4 v[60:63],   v40, %0 offset:768\n\t"
        "global_load_dwordx4 v[64:67],   v40, %0 offset:1024\n\t"
        "global_load_dwordx4 v[68:71],   v40, %0 offset:1280\n\t"
        "global_load_dwordx4 v[72:75],   v40, %0 offset:1536\n\t"
        "global_load_dwordx4 v[76:79],   v40, %0 offset:1792\n\t"
        "global_load_dwordx4 v[80:83],   v40, %0 offset:2048\n\t"
        "global_load_dwordx4 v[84:87],   v40, %0 offset:2304\n\t"
        "global_load_dwordx4 v[88:91],   v40, %0 offset:2560\n\t"
        "global_load_dwordx4 v[92:95],   v40, %0 offset:2816\n\t"
        "global_load_dwordx4 v[96:99],   v40, %0 offset:3072\n\t"
        "global_load_dwordx4 v[100:103], v40, %0 offset:3328\n\t"
        "global_load_dwordx4 v[104:107], v40, %0 offset:3584\n\t"
        "global_load_dwordx4 v[108:111], v40, %0 offset:3840\n\t"
        "v_add_u32 v41, 0x1000, v40\n\t"
        "global_load_dwordx4 v[112:115], v41, %0 offset:0\n\t"
        "global_load_dwordx4 v[116:119], v41, %0 offset:256\n\t"
        "global_load_dwordx4 v[120:123], v41, %0 offset:512\n\t"
        "global_load_dwordx4 v[124:127], v41, %0 offset:768\n\t"
        "global_load_dwordx4 v[128:131], v41, %0 offset:1024\n\t"
        "global_load_dwordx4 v[132:135], v41, %0 offset:1280\n\t"
        "global_load_dwordx4 v[136:139], v41, %0 offset:1536\n\t"
        "global_load_dwordx4 v[140:143], v41, %0 offset:1792\n\t"
        "v_add_u32 v42, 0x1800, v40\n\t"   // load base: 24 groups ahead
        "s_waitcnt vmcnt(0)\n\t"
        "s_mov_b32 s20, 125\n\t"           // 125 passes x 6 SBs x 4 groups = 3000
        "3:\n\t"
        SCQ("48","49","50","51",  "52","53","54","55",
            "56","57","58","59",  "60","61","62","63")
        SCQ("64","65","66","67",  "68","69","70","71",
            "72","73","74","75",  "76","77","78","79")
        SCQ("80","81","82","83",  "84","85","86","87",
            "88","89","90","91",  "92","93","94","95")
        SCQ("96","97","98","99",  "100","101","102","103",
            "104","105","106","107", "108","109","110","111")
        SCQ("112","113","114","115", "116","117","118","119",
            "120","121","122","123", "124","125","126","127")
        SCQ("128","129","130","131", "132","133","134","135",
            "136","137","138","139", "140","141","142","143")
        "s_sub_u32 s20, s20, 1\n\t"
        "s_cmp_lg_u32 s20, 0\n\t"
        "s_cbranch_scc1 3b\n\t"
        "s_waitcnt vmcnt(0)\n\t"
        :
        : "s"(consq), "s"(CSq), "v"(voff)
        : "v40", "v41", "v42", "v43",
          "v48", "v49", "v50", "v51", "v52", "v53", "v54", "v55",
          "v56", "v57", "v58", "v59", "v60", "v61", "v62", "v63",
          "v64", "v65", "v66", "v67", "v68", "v69", "v70", "v71",
          "v72", "v73", "v74", "v75", "v76", "v77", "v78", "v79",
          "v80", "v81", "v82", "v83", "v84", "v85", "v86", "v87",
          "v88", "v89", "v90", "v91", "v92", "v93", "v94", "v95",
          "v96", "v97", "v98", "v99", "v100", "v101", "v102", "v103",
          "v104", "v105", "v106", "v107", "v108", "v109", "v110", "v111",
          "v112", "v113", "v114", "v115", "v116", "v117", "v118", "v119",
          "v120", "v121", "v122", "v123", "v124", "v125", "v126", "v127",
          "v128", "v129", "v130", "v131", "v132", "v133", "v134", "v135",
          "v136", "v137", "v138", "v139", "v140", "v141", "v142", "v143",
          "s20", "scc", "memory");
}

// kD: flags ONLY — per-iteration "any nonzero adjustment" on the
// never-done trajectory. k_final recomputes step/cand (bitwise same).
__global__ void kD_flags(const float* __restrict__ cons,
                         const float* __restrict__ CSq,
                         const float* __restrict__ init,
                         unsigned int* __restrict__ counts) {
    const int idx = blockIdx.x * 256 + threadIdx.x;
    const int b = idx / TT;
    const int t = idx - b * TT;
    __shared__ unsigned sflag[5];
    if (threadIdx.x < 5) sflag[threadIdx.x] = 0u;
    __syncthreads();

    int lo = t - 2; if (lo < 0) lo = 0;
    int hi = t + 3; if (hi > TT) hi = TT;
    int uh = hi - 1;
    float csH = CSq[((uh >> 2) * 16 + b) * 4 + (uh & 3)];
    float csL = 0.f;
    if (lo > 0) {
        int ul = lo - 1;
        csL = CSq[((ul >> 2) * 16 + b) * 4 + (ul & 3)];
    }
    float local = (csH - csL) / (float)(hi - lo);
    float dir = (local > 0.7f) ? -0.1f : ((local < 0.4f) ? 0.1f : 0.0f);
    bool interior = (t >= 1) && (t <= TT - 2);
    float step = interior ? dir : 0.0f;
    float g = (t == 0) ? 0.f : fabsf(cons[idx] - cons[idx - 1]);
    float cand = (g > 0.15f) ? 1.f : 0.f;
    float r = init[idx];
    bool nz[5];
#pragma unroll
    for (int j = 0; j < 5; ++j) {
        float adj = (fmaxf(cand, r) > 0.5f) ? step : 0.0f;
        nz[j] = (adj != 0.0f);
        r = fminf(fmaxf(r + adj, 0.0f), 1.0f);
    }
    const int lane = threadIdx.x & 63;
#pragma unroll
    for (int j = 0; j < 5; ++j) {
        unsigned long long mb = __ballot(nz[j]);
        if (lane == 0 && mb) atomicOr(&sflag[j], 1u);   // LDS-scope, cheap
    }
    __syncthreads();
    if (threadIdx.x < 5 && sflag[threadIdx.x]) counts[threadIdx.x] = 1u;
}

// K_final: recompute step/cand (bitwise same as kD) and replay the 5-iter
// trajectory, freezing at the first iteration whose flag is 0.
__global__ void k_final(const float* __restrict__ cons,
                        const float* __restrict__ CSq,
                        const float* __restrict__ init,
                        const unsigned int* __restrict__ counts,
                        float* __restrict__ outp) {
    const int idx = blockIdx.x * 256 + threadIdx.x;
    const int b = idx / TT;
    const int t = idx - b * TT;

    int lo = t - 2; if (lo < 0) lo = 0;
    int hi = t + 3; if (hi > TT) hi = TT;
    int uh = hi - 1;
    float csH = CSq[((uh >> 2) * 16 + b) * 4 + (uh & 3)];
    float csL = 0.f;
    if (lo > 0) {
        int ul = lo - 1;
        csL = CSq[((ul >> 2) * 16 + b) * 4 + (ul & 3)];
    }
    float local = (csH - csL) / (float)(hi - lo);
    float dir = (local > 0.7f) ? -0.1f : ((local < 0.4f) ? 0.1f : 0.0f);
    bool interior = (t >= 1) && (t <= TT - 2);
    float step = interior ? dir : 0.0f;
    float g = (t == 0) ? 0.f : fabsf(cons[idx] - cons[idx - 1]);
    float cand = (g > 0.15f) ? 1.f : 0.f;

    float r = init[idx];
    unsigned c[5];
#pragma unroll
    for (int j = 0; j < 5; ++j) c[j] = counts[j];
#pragma unroll
    for (int j = 0; j < 5; ++j) {
        if (c[j] == 0u) break;
        float adj = (fmaxf(cand, r) > 0.5f) ? step : 0.0f;
        r = fminf(fmaxf(r + adj, 0.0f), 1.0f);
    }
    outp[idx] = r;
}

extern "C" void kernel_launch(void* const* d_in, const int* in_sizes, int n_in,
                              void* d_out, int out_size, void* d_ws, size_t ws_size,
                              hipStream_t stream) {
    const float* mel  = (const float*)d_in[0];
    const float* spec = (const float*)d_in[1];
    const float* init = (const float*)d_in[2];
    const float* wts  = (const float*)d_in[3];

    float* ws = (float*)d_ws;
    float* ssq   = ws;                 // 192000
    float* dotv  = ws + 192000;        // 192000
    float* cmean = ws + 384000;        // 192000
    float* cons  = ws + 576000;        // 192000 (row-major, for grads)
    float* consq = ws + 768000;        // 192000 (Q4-interleaved)
    float* CSq   = ws + 960000;        // 198144 (Q4; absorbs tail prefetch/warm over-read)
    float* temporal = ws + 1158144;    // 16
    unsigned int* counts = (unsigned int*)(ws + 1158160); // 8 u32

    dim3 g1((TT + 255) / 256, BB);
    k1_colstats<<<g1, 256, 0, stream>>>(mel, ssq, dotv, cmean, counts);
    kA_temporal<<<BB, 256, 0, stream>>>(cmean, temporal);
    kB_cons<<<BT / 256, 256, 0, stream>>>(ssq, dotv, spec, temporal, wts, cons, consq);
    kC_scan16<<<1, 256, 0, stream>>>(consq, CSq);
    kD_flags<<<BT / 256, 256, 0, stream>>>(cons, CSq, init, counts);
    k_final<<<BT / 256, 256, 0, stream>>>(cons, CSq, init, counts, (float*)d_out);
}

// Round 26
// 121.891 us; speedup vs baseline: 1.0515x; 1.0291x over previous
//
#include <hip/hip_runtime.h>
#include <cstdint>

#define BB 16
#define MM 128
#define TT 12000
constexpr int BT = BB * TT; // 192000

// Q4-interleaved scan layout: element (row b, pos t), t=4g+j lives at
// q[(g*16 + b)*4 + j]  (one float4 per (group, row); 16 rows contiguous
// per group -> a 16-lane quad access covers 256 contiguous bytes).

// K1: per-column stats over the M axis, sequential in m (reference order).
// anti-fma via `#pragma clang fp contract(off)` (proven round 13).
__global__ void k1_colstats(const float* __restrict__ mel,
                            float* __restrict__ ssq,
                            float* __restrict__ dotv,
                            float* __restrict__ cmean,
                            unsigned int* __restrict__ counts) {
    if (blockIdx.x == 0 && blockIdx.y == 0 && threadIdx.x < 8)
        counts[threadIdx.x] = 0u;
    const int b = blockIdx.y;
    const int t = blockIdx.x * blockDim.x + threadIdx.x;
    if (t >= TT) return;
    const float* base = mel + (size_t)b * MM * TT;
    float accd = 0.f, accq = 0.f, accs = 0.f;
    {
#pragma clang fp contract(off)
        for (int m = 0; m < MM; ++m) {
            const float* rowp = base + (size_t)m * TT;
            float cur = rowp[t];
            float prev = (t > 0) ? rowp[t - 1] : 0.f;
            accd += prev * cur;
            accq += cur * cur;
            accs += cur;
        }
    }
    size_t i = (size_t)b * TT + t;
    ssq[i] = accq; dotv[i] = accd; cmean[i] = accs * (1.0f / MM);
}

// kA: temporal = 1 - std(smooth, ddof=1). Row staged to LDS once.
__global__ void kA_temporal(const float* __restrict__ cmean,
                            float* __restrict__ temporal) {
    const int b = blockIdx.x;
    const int tid = threadIdx.x;
    __shared__ __align__(16) float row_s[TT];
    __shared__ float red[256];
    __shared__ float mean_s;
    const float4* c4 = (const float4*)(cmean + (size_t)b * TT);
    float4* r4 = (float4*)row_s;
    for (int i = tid; i < TT / 4; i += 256) r4[i] = c4[i];
    __syncthreads();

    float s = 0.f;
    for (int t = tid; t < TT; t += 256) {
        float v = 0.f;
        int lo = t - 2 < 0 ? 0 : t - 2;
        int hi = t + 2 >= TT ? TT - 1 : t + 2;
        for (int j = lo; j <= hi; ++j) v += row_s[j];
        s += v / 5.0f;
    }
    red[tid] = s; __syncthreads();
    for (int o = 128; o > 0; o >>= 1) {
        if (tid < o) red[tid] += red[tid + o];
        __syncthreads();
    }
    if (tid == 0) mean_s = red[0] / (float)TT;
    __syncthreads();
    float mean = mean_s;
    float ss = 0.f;
    for (int t = tid; t < TT; t += 256) {
        float v = 0.f;
        int lo = t - 2 < 0 ? 0 : t - 2;
        int hi = t + 2 >= TT ? TT - 1 : t + 2;
        for (int j = lo; j <= hi; ++j) v += row_s[j];
        float sm = v / 5.0f - mean;
        ss += sm * sm;
    }
    red[tid] = ss; __syncthreads();
    for (int o = 128; o > 0; o >>= 1) {
        if (tid < o) red[tid] += red[tid + o];
        __syncthreads();
    }
    if (tid == 0) {
        float var = red[0] / (float)(TT - 1);
        temporal[b] = 1.0f - sqrtf(var);
    }
}

// kB: cons — same arithmetic as the passing version; additionally writes
// the Q4-interleaved copy for the scan (same value, extra store only).
__global__ void kB_cons(const float* __restrict__ ssq,
                        const float* __restrict__ dotv,
                        const float* __restrict__ spec,
                        const float* __restrict__ temporal,
                        const float* __restrict__ wraw,
                        float* __restrict__ cons,
                        float* __restrict__ consq) {
    const int idx = blockIdx.x * 256 + threadIdx.x;
    const int b = idx / TT;
    const int t = idx - b * TT;
    float x0 = wraw[0], x1 = wraw[1], x2 = wraw[2];
    float mx = fmaxf(x0, fmaxf(x1, x2));
    float e0 = expf(x0 - mx), e1 = expf(x1 - mx), e2 = expf(x2 - mx);
    float es = (e0 + e1) + e2;
    float w0 = e0 / es, w1 = e1 / es, w2 = e2 / es;
    float mel_sim, spec_sim;
    if (t == 0) { mel_sim = 0.f; spec_sim = 1.f; }
    else {
        float na = fmaxf(sqrtf(ssq[idx - 1]), 1e-8f);
        float nb = fmaxf(sqrtf(ssq[idx]),     1e-8f);
        float den = na * nb; asm volatile("" : "+v"(den));
        mel_sim = dotv[idx] / den;
        float d = fabsf(spec[idx] - spec[idx - 1]);
        spec_sim = 1.0f / (1.0f + d);
    }
    float pa = w0 * mel_sim;     asm volatile("" : "+v"(pa));
    float pb = w1 * spec_sim;    asm volatile("" : "+v"(pb));
    float pc = w2 * temporal[b]; asm volatile("" : "+v"(pc));
    float c = (pa + pb) + pc;
    cons[idx] = c;
    consq[((t >> 2) * 16 + b) * 4 + (t & 3)] = c;
}

// 4 chained adds: carry enters via P's last reg, leaves in d.
#define QCH(P, a, b, c, d) \
    "v_add_f32 v" a ", v" P ", v" a "\n\t" \
    "v_add_f32 v" b ", v" a ", v" b "\n\t" \
    "v_add_f32 v" c ", v" b ", v" c "\n\t" \
    "v_add_f32 v" d ", v" c ", v" d "\n\t"

// One SB (8 groups = 32 elems, 16 lanes lockstep): ONE vmcnt(32) wait
// (ring = 3 SBs x 16 ops; my 8 operand loads are 32 ops old — FIFO-exact),
// 32 chained adds (bitwise reference order), carry snapshot BEFORE the
// prefetch loads (round-5 WAR discipline), 8 Q4 stores (256 contiguous
// bytes each), 8 prefetch loads 24 groups ahead, pointer bumps.
#define SB8(a0,a1,a2,a3, b0,b1,b2,b3, c0,c1,c2,c3, d0,d1,d2,d3, \
            e0,e1,e2,e3, f0,f1,f2,f3, g0,g1,g2,g3, h0,h1,h2,h3) \
    "s_waitcnt vmcnt(32)\n\t" \
    QCH("43", a0, a1, a2, a3) \
    QCH(a3,   b0, b1, b2, b3) \
    QCH(b3,   c0, c1, c2, c3) \
    QCH(c3,   d0, d1, d2, d3) \
    QCH(d3,   e0, e1, e2, e3) \
    QCH(e3,   f0, f1, f2, f3) \
    QCH(f3,   g0, g1, g2, g3) \
    QCH(g3,   h0, h1, h2, h3) \
    "v_mov_b32 v43, v" h3 "\n\t" \
    "global_store_dwordx4 v40, v[" a0 ":" a3 "], %1 offset:0\n\t" \
    "global_store_dwordx4 v40, v[" b0 ":" b3 "], %1 offset:256\n\t" \
    "global_store_dwordx4 v40, v[" c0 ":" c3 "], %1 offset:512\n\t" \
    "global_store_dwordx4 v40, v[" d0 ":" d3 "], %1 offset:768\n\t" \
    "global_store_dwordx4 v40, v[" e0 ":" e3 "], %1 offset:1024\n\t" \
    "global_store_dwordx4 v40, v[" f0 ":" f3 "], %1 offset:1280\n\t" \
    "global_store_dwordx4 v40, v[" g0 ":" g3 "], %1 offset:1536\n\t" \
    "global_store_dwordx4 v40, v[" h0 ":" h3 "], %1 offset:1792\n\t" \
    "global_load_dwordx4 v[" a0 ":" a3 "], v42, %0 offset:0\n\t" \
    "global_load_dwordx4 v[" b0 ":" b3 "], v42, %0 offset:256\n\t" \
    "global_load_dwordx4 v[" c0 ":" c3 "], v42, %0 offset:512\n\t" \
    "global_load_dwordx4 v[" d0 ":" d3 "], v42, %0 offset:768\n\t" \
    "global_load_dwordx4 v[" e0 ":" e3 "], v42, %0 offset:1024\n\t" \
    "global_load_dwordx4 v[" f0 ":" f3 "], v42, %0 offset:1280\n\t" \
    "global_load_dwordx4 v[" g0 ":" g3 "], v42, %0 offset:1536\n\t" \
    "global_load_dwordx4 v[" h0 ":" h3 "], v42, %0 offset:1792\n\t" \
    "v_add_u32 v40, 0x800, v40\n\t" \
    "v_add_u32 v42, 0x800, v42\n\t"

// kC: 16-lane SIMT scan, 8-group SBs (375 waits instead of 750 — halved
// per-SB overhead), 24-group ring, + decoupled L2 warmers (waves 1-3,
// no barriers; round-25 neutral-to-slightly-positive).
__global__ void __launch_bounds__(256)
kC_scan16(const float* __restrict__ consq,
          float* __restrict__ CSq) {
    const int tid = threadIdx.x;
    if (tid >= 64) {
        // warmers: stream all of consq into the local XCD L2.
        const float4* s4 = (const float4*)consq;
        const int lane = tid - 64;
        for (int it = 0; it < 32; ++it) {
            float4 tmp[8];
#pragma unroll
            for (int i = 0; i < 8; ++i)
                tmp[i] = s4[(size_t)it * 1536 + lane + 192 * i];
#pragma unroll
            for (int i = 0; i < 8; ++i)
                asm volatile("" :: "v"(tmp[i].x), "v"(tmp[i].y),
                                   "v"(tmp[i].z), "v"(tmp[i].w));
        }
        return;
    }
    const int r = tid;
    if (r >= BB) return;
    uint32_t voff = (uint32_t)(r * 16);   // per-lane byte offset in a group
    asm volatile(
        "v_mov_b32 v40, %2\n\t"
        "v_mov_b32 v43, 0\n\t"
        // prologue: fill 24-quad ring (groups 0..23)
        "global_load_dwordx4 v[48:51],   v40, %0 offset:0\n\t"
        "global_load_dwordx4 v[52:55],   v40, %0 offset:256\n\t"
        "global_load_dwordx4 v[56:59],   v40, %0 offset:512\n\t"
        "global_load_dwordx4 v[60:63],   v40, %0 offset:768\n\t"
        "global_load_dwordx4 v[64:67],   v40, %0 offset:1024\n\t"
        "global_load_dwordx4 v[68:71],   v40, %0 offset:1280\n\t"
        "global_load_dwordx4 v[72:75],   v40, %0 offset:1536\n\t"
        "global_load_dwordx4 v[76:79],   v40, %0 offset:1792\n\t"
        "global_load_dwordx4 v[80:83],   v40, %0 offset:2048\n\t"
        "global_load_dwordx4 v[84:87],   v40, %0 offset:2304\n\t"
        "global_load_dwordx4 v[88:91],   v40, %0 offset:2560\n\t"
        "global_load_dwordx4 v[92:95],   v40, %0 offset:2816\n\t"
        "global_load_dwordx4 v[96:99],   v40, %0 offset:3072\n\t"
        "global_load_dwordx4 v[100:103], v40, %0 offset:3328\n\t"
        "global_load_dwordx4 v[104:107], v40, %0 offset:3584\n\t"
        "global_load_dwordx4 v[108:111], v40, %0 offset:3840\n\t"
        "v_add_u32 v41, 0x1000, v40\n\t"
        "global_load_dwordx4 v[112:115], v41, %0 offset:0\n\t"
        "global_load_dwordx4 v[116:119], v41, %0 offset:256\n\t"
        "global_load_dwordx4 v[120:123], v41, %0 offset:512\n\t"
        "global_load_dwordx4 v[124:127], v41, %0 offset:768\n\t"
        "global_load_dwordx4 v[128:131], v41, %0 offset:1024\n\t"
        "global_load_dwordx4 v[132:135], v41, %0 offset:1280\n\t"
        "global_load_dwordx4 v[136:139], v41, %0 offset:1536\n\t"
        "global_load_dwordx4 v[140:143], v41, %0 offset:1792\n\t"
        "v_add_u32 v42, 0x1800, v40\n\t"   // load base: 24 groups ahead
        "s_waitcnt vmcnt(0)\n\t"
        "s_mov_b32 s20, 125\n\t"           // 125 passes x 3 SB8 = 3000 groups
        "3:\n\t"
        SB8("48","49","50","51",   "52","53","54","55",
            "56","57","58","59",   "60","61","62","63",
            "64","65","66","67",   "68","69","70","71",
            "72","73","74","75",   "76","77","78","79")
        SB8("80","81","82","83",   "84","85","86","87",
            "88","89","90","91",   "92","93","94","95",
            "96","97","98","99",   "100","101","102","103",
            "104","105","106","107","108","109","110","111")
        SB8("112","113","114","115","116","117","118","119",
            "120","121","122","123","124","125","126","127",
            "128","129","130","131","132","133","134","135",
            "136","137","138","139","140","141","142","143")
        "s_sub_u32 s20, s20, 1\n\t"
        "s_cmp_lg_u32 s20, 0\n\t"
        "s_cbranch_scc1 3b\n\t"
        "s_waitcnt vmcnt(0)\n\t"
        :
        : "s"(consq), "s"(CSq), "v"(voff)
        : "v40", "v41", "v42", "v43",
          "v48", "v49", "v50", "v51", "v52", "v53", "v54", "v55",
          "v56", "v57", "v58", "v59", "v60", "v61", "v62", "v63",
          "v64", "v65", "v66", "v67", "v68", "v69", "v70", "v71",
          "v72", "v73", "v74", "v75", "v76", "v77", "v78", "v79",
          "v80", "v81", "v82", "v83", "v84", "v85", "v86", "v87",
          "v88", "v89", "v90", "v91", "v92", "v93", "v94", "v95",
          "v96", "v97", "v98", "v99", "v100", "v101", "v102", "v103",
          "v104", "v105", "v106", "v107", "v108", "v109", "v110", "v111",
          "v112", "v113", "v114", "v115", "v116", "v117", "v118", "v119",
          "v120", "v121", "v122", "v123", "v124", "v125", "v126", "v127",
          "v128", "v129", "v130", "v131", "v132", "v133", "v134", "v135",
          "v136", "v137", "v138", "v139", "v140", "v141", "v142", "v143",
          "s20", "scc", "memory");
}

// kD: flags ONLY — per-iteration "any nonzero adjustment" on the
// never-done trajectory. k_final recomputes step/cand (bitwise same).
__global__ void kD_flags(const float* __restrict__ cons,
                         const float* __restrict__ CSq,
                         const float* __restrict__ init,
                         unsigned int* __restrict__ counts) {
    const int idx = blockIdx.x * 256 + threadIdx.x;
    const int b = idx / TT;
    const int t = idx - b * TT;
    __shared__ unsigned sflag[5];
    if (threadIdx.x < 5) sflag[threadIdx.x] = 0u;
    __syncthreads();

    int lo = t - 2; if (lo < 0) lo = 0;
    int hi = t + 3; if (hi > TT) hi = TT;
    int uh = hi - 1;
    float csH = CSq[((uh >> 2) * 16 + b) * 4 + (uh & 3)];
    float csL = 0.f;
    if (lo > 0) {
        int ul = lo - 1;
        csL = CSq[((ul >> 2) * 16 + b) * 4 + (ul & 3)];
    }
    float local = (csH - csL) / (float)(hi - lo);
    float dir = (local > 0.7f) ? -0.1f : ((local < 0.4f) ? 0.1f : 0.0f);
    bool interior = (t >= 1) && (t <= TT - 2);
    float step = interior ? dir : 0.0f;
    float g = (t == 0) ? 0.f : fabsf(cons[idx] - cons[idx - 1]);
    float cand = (g > 0.15f) ? 1.f : 0.f;
    float r = init[idx];
    bool nz[5];
#pragma unroll
    for (int j = 0; j < 5; ++j) {
        float adj = (fmaxf(cand, r) > 0.5f) ? step : 0.0f;
        nz[j] = (adj != 0.0f);
        r = fminf(fmaxf(r + adj, 0.0f), 1.0f);
    }
    const int lane = threadIdx.x & 63;
#pragma unroll
    for (int j = 0; j < 5; ++j) {
        unsigned long long mb = __ballot(nz[j]);
        if (lane == 0 && mb) atomicOr(&sflag[j], 1u);   // LDS-scope, cheap
    }
    __syncthreads();
    if (threadIdx.x < 5 && sflag[threadIdx.x]) counts[threadIdx.x] = 1u;
}

// K_final: recompute step/cand (bitwise same as kD) and replay the 5-iter
// trajectory, freezing at the first iteration whose flag is 0.
__global__ void k_final(const float* __restrict__ cons,
                        const float* __restrict__ CSq,
                        const float* __restrict__ init,
                        const unsigned int* __restrict__ counts,
                        float* __restrict__ outp) {
    const int idx = blockIdx.x * 256 + threadIdx.x;
    const int b = idx / TT;
    const int t = idx - b * TT;

    int lo = t - 2; if (lo < 0) lo = 0;
    int hi = t + 3; if (hi > TT) hi = TT;
    int uh = hi - 1;
    float csH = CSq[((uh >> 2) * 16 + b) * 4 + (uh & 3)];
    float csL = 0.f;
    if (lo > 0) {
        int ul = lo - 1;
        csL = CSq[((ul >> 2) * 16 + b) * 4 + (ul & 3)];
    }
    float local = (csH - csL) / (float)(hi - lo);
    float dir = (local > 0.7f) ? -0.1f : ((local < 0.4f) ? 0.1f : 0.0f);
    bool interior = (t >= 1) && (t <= TT - 2);
    float step = interior ? dir : 0.0f;
    float g = (t == 0) ? 0.f : fabsf(cons[idx] - cons[idx - 1]);
    float cand = (g > 0.15f) ? 1.f : 0.f;

    float r = init[idx];
    unsigned c[5];
#pragma unroll
    for (int j = 0; j < 5; ++j) c[j] = counts[j];
#pragma unroll
    for (int j = 0; j < 5; ++j) {
        if (c[j] == 0u) break;
        float adj = (fmaxf(cand, r) > 0.5f) ? step : 0.0f;
        r = fminf(fmaxf(r + adj, 0.0f), 1.0f);
    }
    outp[idx] = r;
}

extern "C" void kernel_launch(void* const* d_in, const int* in_sizes, int n_in,
                              void* d_out, int out_size, void* d_ws, size_t ws_size,
                              hipStream_t stream) {
    const float* mel  = (const float*)d_in[0];
    const float* spec = (const float*)d_in[1];
    const float* init = (const float*)d_in[2];
    const float* wts  = (const float*)d_in[3];

    float* ws = (float*)d_ws;
    float* ssq   = ws;                 // 192000
    float* dotv  = ws + 192000;        // 192000
    float* cmean = ws + 384000;        // 192000
    float* cons  = ws + 576000;        // 192000 (row-major, for grads)
    float* consq = ws + 768000;        // 192000 (Q4-interleaved)
    float* CSq   = ws + 960000;        // 198144 (Q4; absorbs tail prefetch over-read)
    float* temporal = ws + 1158144;    // 16
    unsigned int* counts = (unsigned int*)(ws + 1158160); // 8 u32

    dim3 g1((TT + 255) / 256, BB);
    k1_colstats<<<g1, 256, 0, stream>>>(mel, ssq, dotv, cmean, counts);
    kA_temporal<<<BB, 256, 0, stream>>>(cmean, temporal);
    kB_cons<<<BT / 256, 256, 0, stream>>>(ssq, dotv, spec, temporal, wts, cons, consq);
    kC_scan16<<<1, 256, 0, stream>>>(consq, CSq);
    kD_flags<<<BT / 256, 256, 0, stream>>>(cons, CSq, init, counts);
    k_final<<<BT / 256, 256, 0, stream>>>(cons, CSq, init, counts, (float*)d_out);
}